// Round 25
// baseline (193.315 us; speedup 1.0000x reference)
//
#include <hip/hip_runtime.h>

typedef unsigned short u16;
typedef __bf16 bf16x8 __attribute__((ext_vector_type(8)));
typedef __bf16 bf16x4 __attribute__((ext_vector_type(4)));
typedef float f32x4 __attribute__((ext_vector_type(4)));

__device__ __forceinline__ u16 f2b(float f) {
    __bf16 h = (__bf16)f;
    return __builtin_bit_cast(u16, h);
}
__device__ __forceinline__ unsigned pk2(float a, float b) {
    return (unsigned)f2b(a) | ((unsigned)f2b(b) << 16);
}

// Bijective XCD-chunked remap: each XCD owns a CONTIGUOUS range of logical block ids.
__device__ __forceinline__ int xcd_chunk(int wg, int n) {
    int q = n >> 3, r = n & 7;
    int x = wg & 7, i = wg >> 3;
    return (x < r ? x * (q + 1) : r * (q + 1) + (x - r) * q) + i;
}

#define GLOAD_LDS16(src, dst)                                              \
    __builtin_amdgcn_global_load_lds(                                      \
        (const __attribute__((address_space(1))) void*)(src),              \
        (__attribute__((address_space(3))) void*)(dst), 16, 0, 0)

// ---------------- pack x: NHWC fp32 -> patch-order bf16 ----------------
__global__ __launch_bounds__(256) void k_pack_x(const float* __restrict__ x,
                                                u16* __restrict__ xp) {
    int v = blockIdx.x * 256 + threadIdx.x;      // 1,806,336 total
    int c0 = (v & 31) << 3;                      // 8-channel chunk
    int pix = v >> 5;                            // 0..56447
    int b = pix / 7056;
    int r = pix - b * 7056;
    int y = r / 84;
    int xx = r - y * 84;
    int opix = (b * 144 + (y / 7) * 12 + (xx / 7)) * 49 + (y % 7) * 7 + (xx % 7);
    const float4* src = reinterpret_cast<const float4*>(x + ((size_t)pix << 8) + c0);
    float4 f0 = src[0], f1 = src[1];
    bf16x8 o = {(__bf16)f0.x, (__bf16)f0.y, (__bf16)f0.z, (__bf16)f0.w,
                (__bf16)f1.x, (__bf16)f1.y, (__bf16)f1.z, (__bf16)f1.w};
    *reinterpret_cast<bf16x8*>(xp + ((size_t)opix << 8) + c0) = o;
}

// ---------------- patch-order -> raster LUT (7056 entries) ----------------
__global__ __launch_bounds__(256) void k_lut(int* __restrict__ lut) {
    int q = blockIdx.x * 256 + threadIdx.x;
    if (q >= 7056) return;
    int pi = q / 49, pos = q - pi * 49;
    int y = (pi / 12) * 7 + pos / 7;
    int xx = (pi - (pi / 12) * 12) * 7 + (pos - (pos / 7) * 7);
    lut[q] = y * 84 + xx;
}

// ---------------- transpose + convert + scale: [R][C] fp32 -> [C][R] bf16 ----------------
// permk!=0: permute out-row index k as k' = (k&~63)|((k&15)<<2)|((k>>4)&3)
__global__ __launch_bounds__(256) void k_tconv(const float* __restrict__ in,
                                               u16* __restrict__ out, int R, int C,
                                               float scale, int permk) {
    __shared__ float tile[32][33];
    int c0 = blockIdx.x << 5, r0 = blockIdx.y << 5;
    int tx = threadIdx.x, ty = threadIdx.y;  // 32 x 8
#pragma unroll
    for (int i = 0; i < 4; i++)
        tile[ty + (i << 3)][tx] = in[(size_t)(r0 + ty + (i << 3)) * C + c0 + tx];
    __syncthreads();
    int k = r0 + tx;
    int kw = permk ? ((k & ~63) | ((k & 15) << 2) | ((k >> 4) & 3)) : k;
#pragma unroll
    for (int i = 0; i < 4; i++)
        out[(size_t)(c0 + ty + (i << 3)) * R + kw] = f2b(tile[tx][ty + (i << 3)] * scale);
}

// ---------------- kv-proj GEMM: [1152,12544] @ [12544,1024], split-K=7 (r24-exact) ----------------
// 128x128 tiles + both-sides XOR swizzle; 512 threads, 8 waves as 2x4 over the tile.
__global__ __launch_bounds__(512) void k_kvproj(const u16* __restrict__ xp,
                                                const u16* __restrict__ wkvT,
                                                float* __restrict__ parts) {
    __shared__ u16 As[8192];   // [128][64]
    __shared__ u16 Bs[8192];   // [128][64]
    const int lin = xcd_chunk(blockIdx.x, 504);
    const int mt = lin % 9;
    const int rest = lin / 9;
    const int nt = rest & 7;
    const int sp = rest >> 3;   // 0..6
    const int tid = threadIdx.x;
    const int wave = tid >> 6, lane = tid & 63;
    const int wr = wave >> 2, wc = wave & 3;   // 2x4 waves over 128x128
    const int lrow = lane & 15, lkg = lane >> 4;
    const u16* Ag = xp + (size_t)(mt * 128) * 12544 + sp * 1792;
    const u16* Bg = wkvT + (size_t)(nt * 128) * 12544 + sp * 1792;
    const int srow = lane >> 3;
    const int scol_sw = (((lane & 7) ^ srow) << 3);  // pre-swizzled source slot
    f32x4 acc[4][2];
#pragma unroll
    for (int m = 0; m < 4; m++)
#pragma unroll
        for (int n = 0; n < 2; n++)
#pragma unroll
            for (int i = 0; i < 4; i++) acc[m][n][i] = 0.f;

    for (int ks = 0; ks < 28; ks++) {
        const int k0 = ks << 6;
        __syncthreads();
#pragma unroll
        for (int j = 0; j < 2; j++) {           // A and B: 16 chunks of 8 rows, 2/wave
            const int c = (wave << 1) + j;
            const int row = (c << 3) + srow;
            GLOAD_LDS16(Ag + (size_t)row * 12544 + k0 + scol_sw, As + (c << 9));
            GLOAD_LDS16(Bg + (size_t)row * 12544 + k0 + scol_sw, Bs + (c << 9));
        }
        __syncthreads();
#pragma unroll
        for (int kk = 0; kk < 2; kk++) {
            const int sig = (kk << 2) + lkg;
            const int sw = ((sig ^ (lrow & 7)) << 3);  // swizzled read slot
            bf16x8 a[4], bb[2];
#pragma unroll
            for (int m = 0; m < 4; m++)
                a[m] = *reinterpret_cast<const bf16x8*>(As + (((wr << 6) + (m << 4) + lrow) << 6) + sw);
#pragma unroll
            for (int n = 0; n < 2; n++)
                bb[n] = *reinterpret_cast<const bf16x8*>(Bs + (((wc << 5) + (n << 4) + lrow) << 6) + sw);
#pragma unroll
            for (int m = 0; m < 4; m++)
#pragma unroll
                for (int n = 0; n < 2; n++)
                    acc[m][n] = __builtin_amdgcn_mfma_f32_16x16x32_bf16(a[m], bb[n], acc[m][n], 0, 0, 0);
        }
    }
    float* outp = parts + (size_t)sp * 1179648;
#pragma unroll
    for (int m = 0; m < 4; m++)
#pragma unroll
        for (int n = 0; n < 2; n++)
#pragma unroll
            for (int i = 0; i < 4; i++) {
                int row = (mt << 7) + (wr << 6) + (m << 4) + (lkg << 2) + i;
                int col = (nt << 7) + (wc << 5) + (n << 4) + lrow;
                outp[(size_t)row * 1024 + col] = acc[m][n][i];
            }
}

// ---------------- reduce 7 split-K partials -> fragment-ordered Kf, kappa-ordered Vf ----------------
// K-side: 4 consecutive n -> same (fc,ks,lg), consecutive e (e0 in {0,4}) -> one 8B store.
__global__ __launch_bounds__(256) void k_kvfin(const float* __restrict__ parts,
                                               u16* __restrict__ Kf, u16* __restrict__ Vf) {
    int v = blockIdx.x * 256 + threadIdx.x;  // < 294912
    int m = v >> 8;
    int n0 = (v & 255) << 2;
    float4 s = {0.f, 0.f, 0.f, 0.f};
#pragma unroll
    for (int sp = 0; sp < 7; sp++) {
        float4 p = *reinterpret_cast<const float4*>(parts + (size_t)sp * 1179648 +
                                                    (size_t)m * 1024 + n0);
        s.x += p.x; s.y += p.y; s.z += p.z; s.w += p.w;
    }
    int b = m / 144, pi = m - b * 144;
    float sv[4] = {s.x, s.y, s.z, s.w};
    if (n0 < 512) {
        int h = n0 >> 6, d0 = n0 & 63;
        int bh = (b << 3) + h;
        int fc = pi >> 4, lr = pi & 15;
        int ks = d0 >> 5, lg = (d0 >> 3) & 3, e0 = d0 & 7;
        bf16x4 kv = {(__bf16)sv[0], (__bf16)sv[1], (__bf16)sv[2], (__bf16)sv[3]};
        *reinterpret_cast<bf16x4*>(
            &Kf[((((size_t)bh * 9 + fc) << 1) + ks) * 512 + (((lg << 4) + lr) << 3) + e0]) = kv;
    } else {
#pragma unroll
        for (int e4 = 0; e4 < 4; e4++) {
            int n = n0 + e4;
            int h = (n & 511) >> 6, d = n & 63;
            int bh = (b << 3) + h;
            int nf = d >> 4, lr = d & 15;
            int ks = pi >> 5;
            int e = (((pi >> 4) & 1) << 2) | (pi & 3);
            int lg = (pi >> 2) & 3;
            Vf[(((size_t)bh * 4 + nf) * 5 + ks) * 512 + (((lg << 4) + lr) << 3) + e] = f2b(sv[e4]);
        }
    }
}

// ---------------- q-proj GEMM -> fragment-ordered Qf; kvproj-style staging (r18-exact) ----------------
__global__ __launch_bounds__(256) void k_qproj(const u16* __restrict__ xp,
                                               const u16* __restrict__ wqT,
                                               u16* __restrict__ Qf) {
    __shared__ u16 As[8192];   // [128][64]
    __shared__ u16 Bs[8192];   // [128][64]
    const int lin = xcd_chunk(blockIdx.x, 1764);
    const int nt = lin & 3, mt = lin >> 2;  // 441 x 4
    const int tid = threadIdx.x;
    const int wave = tid >> 6, lane = tid & 63;
    const int wr = wave >> 1, wc = wave & 1;
    const int lrow = lane & 15, lkg = lane >> 4;
    const u16* Ag = xp + (size_t)(mt * 128) * 256;
    const u16* Bg = wqT + (size_t)(nt * 128) * 256;
    const int srow = lane >> 3;
    const int scol_sw = (((lane & 7) ^ srow) << 3);  // pre-swizzled source slot
    f32x4 acc[4][4];
#pragma unroll
    for (int m = 0; m < 4; m++)
#pragma unroll
        for (int n = 0; n < 4; n++)
#pragma unroll
            for (int i = 0; i < 4; i++) acc[m][n][i] = 0.f;

    for (int ks = 0; ks < 4; ks++) {
        const int k0 = ks << 6;
        __syncthreads();
#pragma unroll
        for (int j = 0; j < 4; j++) {           // A and B: 16 chunks of 8 rows each
            const int c = (wave << 2) + j;
            const int row = (c << 3) + srow;
            GLOAD_LDS16(Ag + (size_t)row * 256 + k0 + scol_sw, As + (c << 9));
            GLOAD_LDS16(Bg + (size_t)row * 256 + k0 + scol_sw, Bs + (c << 9));
        }
        __syncthreads();
#pragma unroll
        for (int kk = 0; kk < 2; kk++) {
            const int sig = (kk << 2) + lkg;
            const int sw = ((sig ^ (lrow & 7)) << 3);  // swizzled read slot
            bf16x8 a[4], bb[4];
#pragma unroll
            for (int m = 0; m < 4; m++)
                a[m] = *reinterpret_cast<const bf16x8*>(As + (((wr << 6) + (m << 4) + lrow) << 6) + sw);
#pragma unroll
            for (int n = 0; n < 4; n++)
                bb[n] = *reinterpret_cast<const bf16x8*>(Bs + (((wc << 6) + (n << 4) + lrow) << 6) + sw);
#pragma unroll
            for (int m = 0; m < 4; m++)
#pragma unroll
                for (int n = 0; n < 4; n++)
                    acc[m][n] = __builtin_amdgcn_mfma_f32_16x16x32_bf16(a[m], bb[n], acc[m][n], 0, 0, 0);
        }
    }
#pragma unroll
    for (int m = 0; m < 4; m++)
#pragma unroll
        for (int n = 0; n < 4; n++)
#pragma unroll
            for (int i = 0; i < 4; i++) {
                int row = (mt << 7) + (wr << 6) + (m << 4) + (lkg << 2) + i;
                int col = (nt << 7) + (wc << 6) + (n << 4) + lrow;  // 0..511
                int b = row / 7056, pp = row - b * 7056;
                int h = col >> 6, d = col & 63;
                int bh = (b << 3) + h;
                int tt = pp >> 4, flr = pp & 15;
                int fks = d >> 5, flg = (d >> 3) & 3, fe = d & 7;
                Qf[((((size_t)bh * 441 + tt) << 1) + fks) * 512 + (((flg << 4) + flr) << 3) + fe] =
                    f2b(acc[m][n][i]);
            }
}

// ---------------- attention: pure-register; 2 waves/block; K/V REGISTER-RESIDENT across
// 7 t-tiles per wave; Q fragments for tile jt+1 prefetched during tile jt (r23-exact).
__global__ __launch_bounds__(128, 2) void k_attn(const u16* __restrict__ Qf,
                                                 const u16* __restrict__ Kf,
                                                 const u16* __restrict__ Vf,
                                                 const int* __restrict__ lut,
                                                 u16* __restrict__ O) {
    const int wv = threadIdx.x >> 6, lane = threadIdx.x & 63;
    const int h = (blockIdx.y << 1) + wv;        // 0..7
    const int b = blockIdx.z;
    const int lrow = lane & 15, lkg = lane >> 4;
    const int bh = (b << 3) + h;
    const int l8 = lane << 3;

    const u16* Kg = Kf + (((size_t)bh * 9) << 10);
    const u16* Vg = Vf + ((size_t)bh * 20) * 512;

    // ---- load K and V fragments ONCE into registers ----
    bf16x8 kf[9][2], vf[4][5];
#pragma unroll
    for (int fc = 0; fc < 9; fc++)
#pragma unroll
        for (int ks = 0; ks < 2; ks++)
            kf[fc][ks] = *reinterpret_cast<const bf16x8*>(Kg + (((fc << 1) + ks) << 9) + l8);
#pragma unroll
    for (int n = 0; n < 4; n++)
#pragma unroll
        for (int ks = 0; ks < 5; ks++)
            vf[n][ks] = *reinterpret_cast<const bf16x8*>(Vg + ((size_t)(n * 5 + ks) << 9) + l8);

    const int t0 = blockIdx.x * 7;               // 63*7 = 441 exactly
    // Q fragments for the first tile
    const u16* Q0 = Qf + ((size_t)(bh * 441 + t0) << 10);
    bf16x8 aq0 = *reinterpret_cast<const bf16x8*>(Q0 + l8);
    bf16x8 aq1 = *reinterpret_cast<const bf16x8*>(Q0 + 512 + l8);

#pragma unroll 1
    for (int jt = 0; jt < 7; jt++) {
        const int t = t0 + jt;

        // ---- prefetch next tile's Q (independent; overlaps softmax+PV below) ----
        const int tn = t0 + (jt < 6 ? jt + 1 : jt);
        const u16* Qn = Qf + ((size_t)(bh * 441 + tn) << 10);
        bf16x8 nq0 = *reinterpret_cast<const bf16x8*>(Qn + l8);
        bf16x8 nq1 = *reinterpret_cast<const bf16x8*>(Qn + 512 + l8);

        // ---- swapped dots: da[fc] = mfma(K_frag, Q_frag) ----
        f32x4 da[9];
#pragma unroll
        for (int fc = 0; fc < 9; fc++)
#pragma unroll
            for (int i = 0; i < 4; i++) da[fc][i] = 0.f;
#pragma unroll
        for (int fc = 0; fc < 9; fc++)
            da[fc] = __builtin_amdgcn_mfma_f32_16x16x32_bf16(kf[fc][0], aq0, da[fc], 0, 0, 0);
#pragma unroll
        for (int fc = 0; fc < 9; fc++)
            da[fc] = __builtin_amdgcn_mfma_f32_16x16x32_bf16(kf[fc][1], aq1, da[fc], 0, 0, 0);

        // ---- softmax for query q=lrow: 36 in-lane + butterfly over the 4 lkg lanes ----
        float mx = -1e30f;
#pragma unroll
        for (int fc = 0; fc < 9; fc++)
#pragma unroll
            for (int i = 0; i < 4; i++) mx = fmaxf(mx, da[fc][i]);
        mx = fmaxf(mx, __shfl_xor(mx, 16));
        mx = fmaxf(mx, __shfl_xor(mx, 32));
        float sum = 0.f;
#pragma unroll
        for (int fc = 0; fc < 9; fc++)
#pragma unroll
            for (int i = 0; i < 4; i++) {
                float v = __expf(da[fc][i] - mx);
                da[fc][i] = v;
                sum += v;
            }
        sum += __shfl_xor(sum, 16);
        sum += __shfl_xor(sum, 32);
        float inv = 1.0f / sum;
        unsigned pw[9][2];
#pragma unroll
        for (int fc = 0; fc < 9; fc++) {
            pw[fc][0] = pk2(da[fc][0] * inv, da[fc][1] * inv);
            pw[fc][1] = pk2(da[fc][2] * inv, da[fc][3] * inv);
        }

        // ---- PV: pa[ks] lane-local (kappa-ordered V, register-resident); 20 MFMA ----
        f32x4 oa[4];
#pragma unroll
        for (int n = 0; n < 4; n++)
#pragma unroll
            for (int i = 0; i < 4; i++) oa[n][i] = 0.f;
#pragma unroll
        for (int ks = 0; ks < 5; ks++) {
            uint4 pav;
            if (ks < 4)
                pav = uint4{pw[2 * ks][0], pw[2 * ks][1], pw[2 * ks + 1][0], pw[2 * ks + 1][1]};
            else
                pav = uint4{pw[8][0], pw[8][1], 0u, 0u};
            bf16x8 pa = __builtin_bit_cast(bf16x8, pav);
#pragma unroll
            for (int n = 0; n < 4; n++)
                oa[n] = __builtin_amdgcn_mfma_f32_16x16x32_bf16(pa, vf[n][ks], oa[n], 0, 0, 0);
        }

        // ---- packed O store via LUT: one 8B bf16x4 per (lane, i) ----
#pragma unroll
        for (int i = 0; i < 4; i++) {
            int q = (t << 4) + (lkg << 2) + i;   // patch-order row within batch
            int rast = lut[q];
            bf16x4 ov = {(__bf16)oa[0][i], (__bf16)oa[1][i], (__bf16)oa[2][i], (__bf16)oa[3][i]};
            *reinterpret_cast<bf16x4*>(O + (((size_t)b * 7056 + rast) << 9) +
                                       (h << 6) + (lrow << 2)) = ov;
        }

        aq0 = nq0;
        aq1 = nq1;
    }
}

// ---------------- out-proj GEMM: [56448,512] @ [512,256] + bias -> fp32 out ----------------
// r24 kvproj transformation applied: 512 threads, 8 waves as 2x4 over the 128x128
// tile (acc[4][2]); doubles resident waves to hide the barrier-drain latency.
__global__ __launch_bounds__(512) void k_outproj(const u16* __restrict__ A,
                                                 const u16* __restrict__ BT,
                                                 const float* __restrict__ bias,
                                                 float* __restrict__ out) {
    __shared__ u16 As[8192];   // [128][64]
    __shared__ u16 Bs[8192];   // [128][64]
    const int lin = xcd_chunk(blockIdx.x, 882);
    const int nt = lin & 1, mt = lin >> 1;
    const int tid = threadIdx.x;
    const int wave = tid >> 6, lane = tid & 63;
    const int wr = wave >> 2, wc = wave & 3;   // 2x4 waves over 128x128
    const int lrow = lane & 15, lkg = lane >> 4;
    const u16* Ag = A + (size_t)(mt * 128) * 512;
    const u16* Bg = BT + (size_t)(nt * 128) * 512;
    const int srow = lane >> 3;
    const int scol_sw = (((lane & 7) ^ srow) << 3);  // pre-swizzled source slot
    f32x4 acc[4][2];
#pragma unroll
    for (int m = 0; m < 4; m++)
#pragma unroll
        for (int n = 0; n < 2; n++)
#pragma unroll
            for (int i = 0; i < 4; i++) acc[m][n][i] = 0.f;

    for (int ks = 0; ks < 8; ks++) {
        const int k0 = ks << 6;
        __syncthreads();
#pragma unroll
        for (int j = 0; j < 2; j++) {           // A and B: 16 chunks of 8 rows, 2/wave
            const int c = (wave << 1) + j;
            const int row = (c << 3) + srow;
            GLOAD_LDS16(Ag + (size_t)row * 512 + k0 + scol_sw, As + (c << 9));
            GLOAD_LDS16(Bg + (size_t)row * 512 + k0 + scol_sw, Bs + (c << 9));
        }
        __syncthreads();
#pragma unroll
        for (int kk = 0; kk < 2; kk++) {
            const int sig = (kk << 2) + lkg;
            const int sw = ((sig ^ (lrow & 7)) << 3);  // swizzled read slot
            bf16x8 a[4], bb[2];
#pragma unroll
            for (int m = 0; m < 4; m++)
                a[m] = *reinterpret_cast<const bf16x8*>(As + (((wr << 6) + (m << 4) + lrow) << 6) + sw);
#pragma unroll
            for (int n = 0; n < 2; n++)
                bb[n] = *reinterpret_cast<const bf16x8*>(Bs + (((wc << 5) + (n << 4) + lrow) << 6) + sw);
#pragma unroll
            for (int m = 0; m < 4; m++)
#pragma unroll
                for (int n = 0; n < 2; n++)
                    acc[m][n] = __builtin_amdgcn_mfma_f32_16x16x32_bf16(a[m], bb[n], acc[m][n], 0, 0, 0);
        }
    }
#pragma unroll
    for (int m = 0; m < 4; m++)
#pragma unroll
        for (int n = 0; n < 2; n++)
#pragma unroll
            for (int i = 0; i < 4; i++) {
                int row = (mt << 7) + (wr << 6) + (m << 4) + (lkg << 2) + i;
                int col = (nt << 7) + (wc << 5) + (n << 4) + lrow;
                out[(size_t)row * 256 + col] = acc[m][n][i] + bias[col];
            }
}

extern "C" void kernel_launch(void* const* d_in, const int* in_sizes, int n_in,
                              void* d_out, int out_size, void* d_ws, size_t ws_size,
                              hipStream_t stream) {
    const float* x = (const float*)d_in[0];
    const float* w_q = (const float*)d_in[1];
    const float* w_kv = (const float*)d_in[2];
    const float* w_out = (const float*)d_in[3];
    const float* b_out = (const float*)d_in[4];
    float* out = (float*)d_out;

    char* ws = (char*)d_ws;
    size_t off = 0;
    auto alloc = [&](size_t bytes) -> char* {
        char* p = ws + off;
        off = (off + bytes + 255) & ~(size_t)255;
        return p;
    };
    // Qf (57.8MB) legally overlays the contiguous dead [wkvT|parts] span (58.7MB).
    u16* xp = (u16*)alloc(28901376ull);         // x, patch order, bf16 [1152][12544]
    u16* wqT = (u16*)alloc(262144ull);          // [512][256], pre-scaled by 0.125
    u16* woutT = (u16*)alloc(262144ull);        // [256][512], k-permuted
    u16* Kf = (u16*)alloc(1179648ull);          // fragment-ordered K
    u16* Vf = (u16*)alloc(1310720ull);          // kappa-ordered V (keys 144..159 zero)
    int* lut = (int*)alloc(28416ull);           // patch-order q -> raster pixel
    u16* O = (u16*)alloc(57802752ull);          // [56448][512] bf16, k'-layout
    u16* wkvT = (u16*)alloc(25690112ull);       // [1024][12544] (dead after k_kvproj)
    float* parts = (float*)alloc(33030144ull);  // [7][1152][1024] fp32 (dead after k_kvfin)
    u16* Qf = (u16*)wkvT;                       // overlay

    hipMemsetAsync(Vf, 0, 1310720ull, stream);  // zero pad keys 144..159
    k_lut<<<28, 256, 0, stream>>>(lut);
    k_pack_x<<<7056, 256, 0, stream>>>(x, xp);
    k_tconv<<<dim3(32, 392), dim3(32, 8), 0, stream>>>(w_kv, wkvT, 12544, 1024, 1.0f, 0);
    k_tconv<<<dim3(16, 8), dim3(32, 8), 0, stream>>>(w_q, wqT, 256, 512, 0.125f, 0);
    k_tconv<<<dim3(8, 16), dim3(32, 8), 0, stream>>>(w_out, woutT, 512, 256, 1.0f, 1);
    k_kvproj<<<504, 512, 0, stream>>>(xp, wkvT, parts);
    k_kvfin<<<1152, 256, 0, stream>>>(parts, Kf, Vf);
    k_qproj<<<1764, 256, 0, stream>>>(xp, wqT, Qf);
    k_attn<<<dim3(63, 4, 8), 128, 0, stream>>>(Qf, Kf, Vf, lut, O);
    k_outproj<<<882, 512, 0, stream>>>(O, woutT, b_out, out);
}

// Round 26
// 190.051 us; speedup vs baseline: 1.0172x; 1.0172x over previous
//
#include <hip/hip_runtime.h>

typedef unsigned short u16;
typedef __bf16 bf16x8 __attribute__((ext_vector_type(8)));
typedef __bf16 bf16x4 __attribute__((ext_vector_type(4)));
typedef float f32x4 __attribute__((ext_vector_type(4)));

__device__ __forceinline__ u16 f2b(float f) {
    __bf16 h = (__bf16)f;
    return __builtin_bit_cast(u16, h);
}
__device__ __forceinline__ unsigned pk2(float a, float b) {
    return (unsigned)f2b(a) | ((unsigned)f2b(b) << 16);
}

// Bijective XCD-chunked remap: each XCD owns a CONTIGUOUS range of logical block ids.
__device__ __forceinline__ int xcd_chunk(int wg, int n) {
    int q = n >> 3, r = n & 7;
    int x = wg & 7, i = wg >> 3;
    return (x < r ? x * (q + 1) : r * (q + 1) + (x - r) * q) + i;
}

#define GLOAD_LDS16(src, dst)                                              \
    __builtin_amdgcn_global_load_lds(                                      \
        (const __attribute__((address_space(1))) void*)(src),              \
        (__attribute__((address_space(3))) void*)(dst), 16, 0, 0)

// ---------------- pack x: NHWC fp32 -> patch-order bf16 ----------------
__global__ __launch_bounds__(256) void k_pack_x(const float* __restrict__ x,
                                                u16* __restrict__ xp) {
    int v = blockIdx.x * 256 + threadIdx.x;      // 1,806,336 total
    int c0 = (v & 31) << 3;                      // 8-channel chunk
    int pix = v >> 5;                            // 0..56447
    int b = pix / 7056;
    int r = pix - b * 7056;
    int y = r / 84;
    int xx = r - y * 84;
    int opix = (b * 144 + (y / 7) * 12 + (xx / 7)) * 49 + (y % 7) * 7 + (xx % 7);
    const float4* src = reinterpret_cast<const float4*>(x + ((size_t)pix << 8) + c0);
    float4 f0 = src[0], f1 = src[1];
    bf16x8 o = {(__bf16)f0.x, (__bf16)f0.y, (__bf16)f0.z, (__bf16)f0.w,
                (__bf16)f1.x, (__bf16)f1.y, (__bf16)f1.z, (__bf16)f1.w};
    *reinterpret_cast<bf16x8*>(xp + ((size_t)opix << 8) + c0) = o;
}

// ---------------- patch-order -> raster LUT (7056 entries) ----------------
__global__ __launch_bounds__(256) void k_lut(int* __restrict__ lut) {
    int q = blockIdx.x * 256 + threadIdx.x;
    if (q >= 7056) return;
    int pi = q / 49, pos = q - pi * 49;
    int y = (pi / 12) * 7 + pos / 7;
    int xx = (pi - (pi / 12) * 12) * 7 + (pos - (pos / 7) * 7);
    lut[q] = y * 84 + xx;
}

// ---------------- transpose + convert + scale: [R][C] fp32 -> [C][R] bf16 ----------------
// permk!=0: permute out-row index k as k' = (k&~63)|((k&15)<<2)|((k>>4)&3)
__global__ __launch_bounds__(256) void k_tconv(const float* __restrict__ in,
                                               u16* __restrict__ out, int R, int C,
                                               float scale, int permk) {
    __shared__ float tile[32][33];
    int c0 = blockIdx.x << 5, r0 = blockIdx.y << 5;
    int tx = threadIdx.x, ty = threadIdx.y;  // 32 x 8
#pragma unroll
    for (int i = 0; i < 4; i++)
        tile[ty + (i << 3)][tx] = in[(size_t)(r0 + ty + (i << 3)) * C + c0 + tx];
    __syncthreads();
    int k = r0 + tx;
    int kw = permk ? ((k & ~63) | ((k & 15) << 2) | ((k >> 4) & 3)) : k;
#pragma unroll
    for (int i = 0; i < 4; i++)
        out[(size_t)(c0 + ty + (i << 3)) * R + kw] = f2b(tile[tx][ty + (i << 3)] * scale);
}

// ---------------- kv-proj GEMM: [1152,12544] @ [12544,1024], split-K=7 (r24-exact) ----------------
// 128x128 tiles + both-sides XOR swizzle; 512 threads, 8 waves as 2x4 over the tile.
__global__ __launch_bounds__(512) void k_kvproj(const u16* __restrict__ xp,
                                                const u16* __restrict__ wkvT,
                                                float* __restrict__ parts) {
    __shared__ u16 As[8192];   // [128][64]
    __shared__ u16 Bs[8192];   // [128][64]
    const int lin = xcd_chunk(blockIdx.x, 504);
    const int mt = lin % 9;
    const int rest = lin / 9;
    const int nt = rest & 7;
    const int sp = rest >> 3;   // 0..6
    const int tid = threadIdx.x;
    const int wave = tid >> 6, lane = tid & 63;
    const int wr = wave >> 2, wc = wave & 3;   // 2x4 waves over 128x128
    const int lrow = lane & 15, lkg = lane >> 4;
    const u16* Ag = xp + (size_t)(mt * 128) * 12544 + sp * 1792;
    const u16* Bg = wkvT + (size_t)(nt * 128) * 12544 + sp * 1792;
    const int srow = lane >> 3;
    const int scol_sw = (((lane & 7) ^ srow) << 3);  // pre-swizzled source slot
    f32x4 acc[4][2];
#pragma unroll
    for (int m = 0; m < 4; m++)
#pragma unroll
        for (int n = 0; n < 2; n++)
#pragma unroll
            for (int i = 0; i < 4; i++) acc[m][n][i] = 0.f;

    for (int ks = 0; ks < 28; ks++) {
        const int k0 = ks << 6;
        __syncthreads();
#pragma unroll
        for (int j = 0; j < 2; j++) {           // A and B: 16 chunks of 8 rows, 2/wave
            const int c = (wave << 1) + j;
            const int row = (c << 3) + srow;
            GLOAD_LDS16(Ag + (size_t)row * 12544 + k0 + scol_sw, As + (c << 9));
            GLOAD_LDS16(Bg + (size_t)row * 12544 + k0 + scol_sw, Bs + (c << 9));
        }
        __syncthreads();
#pragma unroll
        for (int kk = 0; kk < 2; kk++) {
            const int sig = (kk << 2) + lkg;
            const int sw = ((sig ^ (lrow & 7)) << 3);  // swizzled read slot
            bf16x8 a[4], bb[2];
#pragma unroll
            for (int m = 0; m < 4; m++)
                a[m] = *reinterpret_cast<const bf16x8*>(As + (((wr << 6) + (m << 4) + lrow) << 6) + sw);
#pragma unroll
            for (int n = 0; n < 2; n++)
                bb[n] = *reinterpret_cast<const bf16x8*>(Bs + (((wc << 5) + (n << 4) + lrow) << 6) + sw);
#pragma unroll
            for (int m = 0; m < 4; m++)
#pragma unroll
                for (int n = 0; n < 2; n++)
                    acc[m][n] = __builtin_amdgcn_mfma_f32_16x16x32_bf16(a[m], bb[n], acc[m][n], 0, 0, 0);
        }
    }
    float* outp = parts + (size_t)sp * 1179648;
#pragma unroll
    for (int m = 0; m < 4; m++)
#pragma unroll
        for (int n = 0; n < 2; n++)
#pragma unroll
            for (int i = 0; i < 4; i++) {
                int row = (mt << 7) + (wr << 6) + (m << 4) + (lkg << 2) + i;
                int col = (nt << 7) + (wc << 5) + (n << 4) + lrow;
                outp[(size_t)row * 1024 + col] = acc[m][n][i];
            }
}

// ---------------- reduce 7 split-K partials -> fragment-ordered Kf, kappa-ordered Vf ----------------
// K-side: 4 consecutive n -> same (fc,ks,lg), consecutive e (e0 in {0,4}) -> one 8B store.
__global__ __launch_bounds__(256) void k_kvfin(const float* __restrict__ parts,
                                               u16* __restrict__ Kf, u16* __restrict__ Vf) {
    int v = blockIdx.x * 256 + threadIdx.x;  // < 294912
    int m = v >> 8;
    int n0 = (v & 255) << 2;
    float4 s = {0.f, 0.f, 0.f, 0.f};
#pragma unroll
    for (int sp = 0; sp < 7; sp++) {
        float4 p = *reinterpret_cast<const float4*>(parts + (size_t)sp * 1179648 +
                                                    (size_t)m * 1024 + n0);
        s.x += p.x; s.y += p.y; s.z += p.z; s.w += p.w;
    }
    int b = m / 144, pi = m - b * 144;
    float sv[4] = {s.x, s.y, s.z, s.w};
    if (n0 < 512) {
        int h = n0 >> 6, d0 = n0 & 63;
        int bh = (b << 3) + h;
        int fc = pi >> 4, lr = pi & 15;
        int ks = d0 >> 5, lg = (d0 >> 3) & 3, e0 = d0 & 7;
        bf16x4 kv = {(__bf16)sv[0], (__bf16)sv[1], (__bf16)sv[2], (__bf16)sv[3]};
        *reinterpret_cast<bf16x4*>(
            &Kf[((((size_t)bh * 9 + fc) << 1) + ks) * 512 + (((lg << 4) + lr) << 3) + e0]) = kv;
    } else {
#pragma unroll
        for (int e4 = 0; e4 < 4; e4++) {
            int n = n0 + e4;
            int h = (n & 511) >> 6, d = n & 63;
            int bh = (b << 3) + h;
            int nf = d >> 4, lr = d & 15;
            int ks = pi >> 5;
            int e = (((pi >> 4) & 1) << 2) | (pi & 3);
            int lg = (pi >> 2) & 3;
            Vf[(((size_t)bh * 4 + nf) * 5 + ks) * 512 + (((lg << 4) + lr) << 3) + e] = f2b(sv[e4]);
        }
    }
}

// ---------------- q-proj GEMM -> fragment-ordered Qf; kvproj-style staging (r18-exact) ----------------
__global__ __launch_bounds__(256) void k_qproj(const u16* __restrict__ xp,
                                               const u16* __restrict__ wqT,
                                               u16* __restrict__ Qf) {
    __shared__ u16 As[8192];   // [128][64]
    __shared__ u16 Bs[8192];   // [128][64]
    const int lin = xcd_chunk(blockIdx.x, 1764);
    const int nt = lin & 3, mt = lin >> 2;  // 441 x 4
    const int tid = threadIdx.x;
    const int wave = tid >> 6, lane = tid & 63;
    const int wr = wave >> 1, wc = wave & 1;
    const int lrow = lane & 15, lkg = lane >> 4;
    const u16* Ag = xp + (size_t)(mt * 128) * 256;
    const u16* Bg = wqT + (size_t)(nt * 128) * 256;
    const int srow = lane >> 3;
    const int scol_sw = (((lane & 7) ^ srow) << 3);  // pre-swizzled source slot
    f32x4 acc[4][4];
#pragma unroll
    for (int m = 0; m < 4; m++)
#pragma unroll
        for (int n = 0; n < 4; n++)
#pragma unroll
            for (int i = 0; i < 4; i++) acc[m][n][i] = 0.f;

    for (int ks = 0; ks < 4; ks++) {
        const int k0 = ks << 6;
        __syncthreads();
#pragma unroll
        for (int j = 0; j < 4; j++) {           // A and B: 16 chunks of 8 rows each
            const int c = (wave << 2) + j;
            const int row = (c << 3) + srow;
            GLOAD_LDS16(Ag + (size_t)row * 256 + k0 + scol_sw, As + (c << 9));
            GLOAD_LDS16(Bg + (size_t)row * 256 + k0 + scol_sw, Bs + (c << 9));
        }
        __syncthreads();
#pragma unroll
        for (int kk = 0; kk < 2; kk++) {
            const int sig = (kk << 2) + lkg;
            const int sw = ((sig ^ (lrow & 7)) << 3);  // swizzled read slot
            bf16x8 a[4], bb[4];
#pragma unroll
            for (int m = 0; m < 4; m++)
                a[m] = *reinterpret_cast<const bf16x8*>(As + (((wr << 6) + (m << 4) + lrow) << 6) + sw);
#pragma unroll
            for (int n = 0; n < 4; n++)
                bb[n] = *reinterpret_cast<const bf16x8*>(Bs + (((wc << 6) + (n << 4) + lrow) << 6) + sw);
#pragma unroll
            for (int m = 0; m < 4; m++)
#pragma unroll
                for (int n = 0; n < 4; n++)
                    acc[m][n] = __builtin_amdgcn_mfma_f32_16x16x32_bf16(a[m], bb[n], acc[m][n], 0, 0, 0);
        }
    }
#pragma unroll
    for (int m = 0; m < 4; m++)
#pragma unroll
        for (int n = 0; n < 4; n++)
#pragma unroll
            for (int i = 0; i < 4; i++) {
                int row = (mt << 7) + (wr << 6) + (m << 4) + (lkg << 2) + i;
                int col = (nt << 7) + (wc << 6) + (n << 4) + lrow;  // 0..511
                int b = row / 7056, pp = row - b * 7056;
                int h = col >> 6, d = col & 63;
                int bh = (b << 3) + h;
                int tt = pp >> 4, flr = pp & 15;
                int fks = d >> 5, flg = (d >> 3) & 3, fe = d & 7;
                Qf[((((size_t)bh * 441 + tt) << 1) + fks) * 512 + (((flg << 4) + flr) << 3) + fe] =
                    f2b(acc[m][n][i]);
            }
}

// ---------------- attention: pure-register; 2 waves/block; K/V REGISTER-RESIDENT across
// 7 t-tiles per wave; Q fragments for tile jt+1 prefetched during tile jt (r23-exact).
__global__ __launch_bounds__(128, 2) void k_attn(const u16* __restrict__ Qf,
                                                 const u16* __restrict__ Kf,
                                                 const u16* __restrict__ Vf,
                                                 const int* __restrict__ lut,
                                                 u16* __restrict__ O) {
    const int wv = threadIdx.x >> 6, lane = threadIdx.x & 63;
    const int h = (blockIdx.y << 1) + wv;        // 0..7
    const int b = blockIdx.z;
    const int lrow = lane & 15, lkg = lane >> 4;
    const int bh = (b << 3) + h;
    const int l8 = lane << 3;

    const u16* Kg = Kf + (((size_t)bh * 9) << 10);
    const u16* Vg = Vf + ((size_t)bh * 20) * 512;

    // ---- load K and V fragments ONCE into registers ----
    bf16x8 kf[9][2], vf[4][5];
#pragma unroll
    for (int fc = 0; fc < 9; fc++)
#pragma unroll
        for (int ks = 0; ks < 2; ks++)
            kf[fc][ks] = *reinterpret_cast<const bf16x8*>(Kg + (((fc << 1) + ks) << 9) + l8);
#pragma unroll
    for (int n = 0; n < 4; n++)
#pragma unroll
        for (int ks = 0; ks < 5; ks++)
            vf[n][ks] = *reinterpret_cast<const bf16x8*>(Vg + ((size_t)(n * 5 + ks) << 9) + l8);

    const int t0 = blockIdx.x * 7;               // 63*7 = 441 exactly
    // Q fragments for the first tile
    const u16* Q0 = Qf + ((size_t)(bh * 441 + t0) << 10);
    bf16x8 aq0 = *reinterpret_cast<const bf16x8*>(Q0 + l8);
    bf16x8 aq1 = *reinterpret_cast<const bf16x8*>(Q0 + 512 + l8);

#pragma unroll 1
    for (int jt = 0; jt < 7; jt++) {
        const int t = t0 + jt;

        // ---- prefetch next tile's Q (independent; overlaps softmax+PV below) ----
        const int tn = t0 + (jt < 6 ? jt + 1 : jt);
        const u16* Qn = Qf + ((size_t)(bh * 441 + tn) << 10);
        bf16x8 nq0 = *reinterpret_cast<const bf16x8*>(Qn + l8);
        bf16x8 nq1 = *reinterpret_cast<const bf16x8*>(Qn + 512 + l8);

        // ---- swapped dots: da[fc] = mfma(K_frag, Q_frag) ----
        f32x4 da[9];
#pragma unroll
        for (int fc = 0; fc < 9; fc++)
#pragma unroll
            for (int i = 0; i < 4; i++) da[fc][i] = 0.f;
#pragma unroll
        for (int fc = 0; fc < 9; fc++)
            da[fc] = __builtin_amdgcn_mfma_f32_16x16x32_bf16(kf[fc][0], aq0, da[fc], 0, 0, 0);
#pragma unroll
        for (int fc = 0; fc < 9; fc++)
            da[fc] = __builtin_amdgcn_mfma_f32_16x16x32_bf16(kf[fc][1], aq1, da[fc], 0, 0, 0);

        // ---- softmax for query q=lrow: 36 in-lane + butterfly over the 4 lkg lanes ----
        float mx = -1e30f;
#pragma unroll
        for (int fc = 0; fc < 9; fc++)
#pragma unroll
            for (int i = 0; i < 4; i++) mx = fmaxf(mx, da[fc][i]);
        mx = fmaxf(mx, __shfl_xor(mx, 16));
        mx = fmaxf(mx, __shfl_xor(mx, 32));
        float sum = 0.f;
#pragma unroll
        for (int fc = 0; fc < 9; fc++)
#pragma unroll
            for (int i = 0; i < 4; i++) {
                float v = __expf(da[fc][i] - mx);
                da[fc][i] = v;
                sum += v;
            }
        sum += __shfl_xor(sum, 16);
        sum += __shfl_xor(sum, 32);
        float inv = 1.0f / sum;
        unsigned pw[9][2];
#pragma unroll
        for (int fc = 0; fc < 9; fc++) {
            pw[fc][0] = pk2(da[fc][0] * inv, da[fc][1] * inv);
            pw[fc][1] = pk2(da[fc][2] * inv, da[fc][3] * inv);
        }

        // ---- PV: pa[ks] lane-local (kappa-ordered V, register-resident); 20 MFMA ----
        f32x4 oa[4];
#pragma unroll
        for (int n = 0; n < 4; n++)
#pragma unroll
            for (int i = 0; i < 4; i++) oa[n][i] = 0.f;
#pragma unroll
        for (int ks = 0; ks < 5; ks++) {
            uint4 pav;
            if (ks < 4)
                pav = uint4{pw[2 * ks][0], pw[2 * ks][1], pw[2 * ks + 1][0], pw[2 * ks + 1][1]};
            else
                pav = uint4{pw[8][0], pw[8][1], 0u, 0u};
            bf16x8 pa = __builtin_bit_cast(bf16x8, pav);
#pragma unroll
            for (int n = 0; n < 4; n++)
                oa[n] = __builtin_amdgcn_mfma_f32_16x16x32_bf16(pa, vf[n][ks], oa[n], 0, 0, 0);
        }

        // ---- packed O store via LUT: one 8B bf16x4 per (lane, i) ----
#pragma unroll
        for (int i = 0; i < 4; i++) {
            int q = (t << 4) + (lkg << 2) + i;   // patch-order row within batch
            int rast = lut[q];
            bf16x4 ov = {(__bf16)oa[0][i], (__bf16)oa[1][i], (__bf16)oa[2][i], (__bf16)oa[3][i]};
            *reinterpret_cast<bf16x4*>(O + (((size_t)b * 7056 + rast) << 9) +
                                       (h << 6) + (lrow << 2)) = ov;
        }

        aq0 = nq0;
        aq1 = nq1;
    }
}

// ---------------- out-proj GEMM: [56448,512] @ [512,256] + bias -> fp32 out (r24-exact) ----------------
__global__ __launch_bounds__(256) void k_outproj(const u16* __restrict__ A,
                                                 const u16* __restrict__ BT,
                                                 const float* __restrict__ bias,
                                                 float* __restrict__ out) {
    __shared__ u16 As[8192];   // [128][64]
    __shared__ u16 Bs[8192];   // [128][64]
    const int lin = xcd_chunk(blockIdx.x, 882);
    const int nt = lin & 1, mt = lin >> 1;
    const int tid = threadIdx.x;
    const int wave = tid >> 6, lane = tid & 63;
    const int wr = wave >> 1, wc = wave & 1;
    const int lrow = lane & 15, lkg = lane >> 4;
    const u16* Ag = A + (size_t)(mt * 128) * 512;
    const u16* Bg = BT + (size_t)(nt * 128) * 512;
    const int srow = lane >> 3;
    const int scol_sw = (((lane & 7) ^ srow) << 3);  // pre-swizzled source slot
    f32x4 acc[4][4];
#pragma unroll
    for (int m = 0; m < 4; m++)
#pragma unroll
        for (int n = 0; n < 4; n++)
#pragma unroll
            for (int i = 0; i < 4; i++) acc[m][n][i] = 0.f;

    for (int ks = 0; ks < 8; ks++) {
        const int k0 = ks << 6;
        __syncthreads();
#pragma unroll
        for (int j = 0; j < 4; j++) {           // A and B: 16 chunks of 8 rows each
            const int c = (wave << 2) + j;
            const int row = (c << 3) + srow;
            GLOAD_LDS16(Ag + (size_t)row * 512 + k0 + scol_sw, As + (c << 9));
            GLOAD_LDS16(Bg + (size_t)row * 512 + k0 + scol_sw, Bs + (c << 9));
        }
        __syncthreads();
#pragma unroll
        for (int kk = 0; kk < 2; kk++) {
            const int sig = (kk << 2) + lkg;
            const int sw = ((sig ^ (lrow & 7)) << 3);  // swizzled read slot
            bf16x8 a[4], bb[4];
#pragma unroll
            for (int m = 0; m < 4; m++)
                a[m] = *reinterpret_cast<const bf16x8*>(As + (((wr << 6) + (m << 4) + lrow) << 6) + sw);
#pragma unroll
            for (int n = 0; n < 4; n++)
                bb[n] = *reinterpret_cast<const bf16x8*>(Bs + (((wc << 6) + (n << 4) + lrow) << 6) + sw);
#pragma unroll
            for (int m = 0; m < 4; m++)
#pragma unroll
                for (int n = 0; n < 4; n++)
                    acc[m][n] = __builtin_amdgcn_mfma_f32_16x16x32_bf16(a[m], bb[n], acc[m][n], 0, 0, 0);
        }
    }
#pragma unroll
    for (int m = 0; m < 4; m++)
#pragma unroll
        for (int n = 0; n < 4; n++)
#pragma unroll
            for (int i = 0; i < 4; i++) {
                int row = (mt << 7) + (wr << 6) + (m << 4) + (lkg << 2) + i;
                int col = (nt << 7) + (wc << 6) + (n << 4) + lrow;
                out[(size_t)row * 256 + col] = acc[m][n][i] + bias[col];
            }
}

extern "C" void kernel_launch(void* const* d_in, const int* in_sizes, int n_in,
                              void* d_out, int out_size, void* d_ws, size_t ws_size,
                              hipStream_t stream) {
    const float* x = (const float*)d_in[0];
    const float* w_q = (const float*)d_in[1];
    const float* w_kv = (const float*)d_in[2];
    const float* w_out = (const float*)d_in[3];
    const float* b_out = (const float*)d_in[4];
    float* out = (float*)d_out;

    char* ws = (char*)d_ws;
    size_t off = 0;
    auto alloc = [&](size_t bytes) -> char* {
        char* p = ws + off;
        off = (off + bytes + 255) & ~(size_t)255;
        return p;
    };
    // Qf (57.8MB) legally overlays the contiguous dead [wkvT|parts] span (58.7MB).
    u16* xp = (u16*)alloc(28901376ull);         // x, patch order, bf16 [1152][12544]
    u16* wqT = (u16*)alloc(262144ull);          // [512][256], pre-scaled by 0.125
    u16* woutT = (u16*)alloc(262144ull);        // [256][512], k-permuted
    u16* Kf = (u16*)alloc(1179648ull);          // fragment-ordered K
    u16* Vf = (u16*)alloc(1310720ull);          // kappa-ordered V (keys 144..159 zero)
    int* lut = (int*)alloc(28416ull);           // patch-order q -> raster pixel
    u16* O = (u16*)alloc(57802752ull);          // [56448][512] bf16, k'-layout
    u16* wkvT = (u16*)alloc(25690112ull);       // [1024][12544] (dead after k_kvproj)
    float* parts = (float*)alloc(33030144ull);  // [7][1152][1024] fp32 (dead after k_kvfin)
    u16* Qf = (u16*)wkvT;                       // overlay

    hipMemsetAsync(Vf, 0, 1310720ull, stream);  // zero pad keys 144..159
    k_lut<<<28, 256, 0, stream>>>(lut);
    k_pack_x<<<7056, 256, 0, stream>>>(x, xp);
    k_tconv<<<dim3(32, 392), dim3(32, 8), 0, stream>>>(w_kv, wkvT, 12544, 1024, 1.0f, 0);
    k_tconv<<<dim3(16, 8), dim3(32, 8), 0, stream>>>(w_q, wqT, 256, 512, 0.125f, 0);
    k_tconv<<<dim3(8, 16), dim3(32, 8), 0, stream>>>(w_out, woutT, 512, 256, 1.0f, 1);
    k_kvproj<<<504, 512, 0, stream>>>(xp, wkvT, parts);
    k_kvfin<<<1152, 256, 0, stream>>>(parts, Kf, Vf);
    k_qproj<<<1764, 256, 0, stream>>>(xp, wqT, Qf);
    k_attn<<<dim3(63, 4, 8), 128, 0, stream>>>(Qf, Kf, Vf, lut, O);
    k_outproj<<<882, 256, 0, stream>>>(O, woutT, b_out, out);
}